// Round 1
// baseline (297.602 us; speedup 1.0000x reference)
//
#include <hip/hip_runtime.h>

#define BB 2
#define HH 1024
#define WW 1024
#define MU 5

// ---------------------------------------------------------------------------
// Kernel 1: Sobel (cross-correlation, zero pad), raw magnitude, initial
// tangent field tang = normalize([-s1, s0]), and global max(mag) via
// wave/block reduce + one atomicMax (uint bit-pattern; mag >= 0).
// ---------------------------------------------------------------------------
__global__ __launch_bounds__(256) void sobel_init(
    const float* __restrict__ x,
    float* __restrict__ tang,          // (B,2,H,W)
    float* __restrict__ mag,           // (B,H,W), UN-normalized
    unsigned int* __restrict__ gmax)
{
    const int w = blockIdx.x * 256 + threadIdx.x;
    const int h = blockIdx.y;
    const int b = blockIdx.z;
    const size_t plane = (size_t)HH * WW;
    const float* xb = x + (size_t)b * plane;

    float s0 = 0.f, s1 = 0.f;
    #pragma unroll
    for (int i = -1; i <= 1; ++i) {
        int hh = h + i;
        if (hh < 0 || hh >= HH) continue;
        #pragma unroll
        for (int j = -1; j <= 1; ++j) {
            int ww = w + j;
            if (ww < 0 || ww >= WW) continue;
            float val = xb[(size_t)hh * WW + ww];
            // k  = [[-1,-2,-1],[0,0,0],[1,2,1]]   (s0)
            // k^T= [[-1,0,1],[-2,0,2],[-1,0,1]]   (s1)
            float k0 = (i == 0) ? 0.f : ((i < 0 ? -1.f : 1.f) * (j == 0 ? 2.f : 1.f));
            float k1 = (j == 0) ? 0.f : ((j < 0 ? -1.f : 1.f) * (i == 0 ? 2.f : 1.f));
            s0 = fmaf(k0, val, s0);
            s1 = fmaf(k1, val, s1);
        }
    }

    float m = sqrtf(s0 * s0 + s1 * s1);
    float inv = (m == 0.f) ? 1.f : (1.f / m);
    const size_t cidx = (size_t)h * WW + w;
    mag[(size_t)b * plane + cidx] = m;
    tang[((size_t)b * 2 + 0) * plane + cidx] = -s1 * inv;
    tang[((size_t)b * 2 + 1) * plane + cidx] =  s0 * inv;

    // block max -> global atomicMax
    float wm = m;
    #pragma unroll
    for (int off = 32; off > 0; off >>= 1)
        wm = fmaxf(wm, __shfl_down(wm, off, 64));
    __shared__ float smax[4];
    const int lane = threadIdx.x & 63;
    const int wave = threadIdx.x >> 6;
    if (lane == 0) smax[wave] = wm;
    __syncthreads();
    if (threadIdx.x == 0) {
        float bm = fmaxf(fmaxf(smax[0], smax[1]), fmaxf(smax[2], smax[3]));
        atomicMax(gmax, __float_as_uint(bm));
    }
}

// ---------------------------------------------------------------------------
// Kernel 2: one ETF smoothing pass. VERT=1: taps along H; VERT=0: along W.
// Out-of-image taps contribute exactly 0 (reference zero-pads tang), so skip.
// ---------------------------------------------------------------------------
template <int VERT>
__global__ __launch_bounds__(256) void etf_pass(
    const float* __restrict__ tin,     // (B,2,H,W)
    float* __restrict__ tout,          // (B,2,H,W)
    const float* __restrict__ mag,     // (B,H,W) raw
    const unsigned int* __restrict__ gmax)
{
    const int w = blockIdx.x * 256 + threadIdx.x;
    const int h = blockIdx.y;
    const int b = blockIdx.z;
    const size_t plane = (size_t)HH * WW;

    const float inv_max = 1.f / __uint_as_float(*gmax);
    const float* t0p = tin + ((size_t)b * 2 + 0) * plane;
    const float* t1p = tin + ((size_t)b * 2 + 1) * plane;
    const float* mp  = mag + (size_t)b * plane;

    const size_t cidx = (size_t)h * WW + w;
    const float tx0 = t0p[cidx];
    const float tx1 = t1p[cidx];
    const float mx  = mp[cidx] * inv_max;

    float acc0 = 0.f, acc1 = 0.f;
    #pragma unroll
    for (int d = -MU; d <= MU; ++d) {
        int hh = VERT ? h + d : h;
        int ww = VERT ? w     : w + d;
        if (hh < 0 || hh >= HH || ww < 0 || ww >= WW) continue;
        size_t idx = (size_t)hh * WW + ww;
        float ty0 = t0p[idx];
        float ty1 = t1p[idx];
        float my  = mp[idx] * inv_max;
        float dotv = fmaf(tx0, ty0, tx1 * ty1);
        float wgt  = (tanhf(my - mx) + 1.f) * dotv * 0.5f;
        acc0 = fmaf(ty0, wgt, acc0);
        acc1 = fmaf(ty1, wgt, acc1);
    }

    float m2  = sqrtf(fmaf(acc0, acc0, acc1 * acc1));
    float inv = (m2 == 0.f) ? 1.f : (1.f / m2);
    tout[((size_t)b * 2 + 0) * plane + cidx] = acc0 * inv;
    tout[((size_t)b * 2 + 1) * plane + cidx] = acc1 * inv;
}

extern "C" void kernel_launch(void* const* d_in, const int* in_sizes, int n_in,
                              void* d_out, int out_size, void* d_ws, size_t ws_size,
                              hipStream_t stream)
{
    const float* x = (const float*)d_in[0];      // (2,1,1024,1024) fp32
    float* tangA = (float*)d_out;                // ping buffer A == output
    char* ws = (char*)d_ws;
    const size_t plane = (size_t)HH * WW;

    float* tangB = (float*)ws;                                   // 16 MB
    float* mag   = (float*)(ws + sizeof(float) * BB * 2 * plane); // 8 MB
    unsigned int* gmax = (unsigned int*)(ws + sizeof(float) * BB * 3 * plane);

    hipMemsetAsync(gmax, 0, sizeof(unsigned int), stream);

    dim3 blk(256, 1, 1);
    dim3 grd(WW / 256, HH, BB);

    sobel_init<<<grd, blk, 0, stream>>>(x, tangA, mag, gmax);

    // 3 iterations x (Vertical, Horizontal); ping-pong ends in tangA == d_out
    etf_pass<1><<<grd, blk, 0, stream>>>(tangA, tangB, mag, gmax);
    etf_pass<0><<<grd, blk, 0, stream>>>(tangB, tangA, mag, gmax);
    etf_pass<1><<<grd, blk, 0, stream>>>(tangA, tangB, mag, gmax);
    etf_pass<0><<<grd, blk, 0, stream>>>(tangB, tangA, mag, gmax);
    etf_pass<1><<<grd, blk, 0, stream>>>(tangA, tangB, mag, gmax);
    etf_pass<0><<<grd, blk, 0, stream>>>(tangB, tangA, mag, gmax);
}

// Round 2
// 252.760 us; speedup vs baseline: 1.1774x; 1.1774x over previous
//
#include <hip/hip_runtime.h>

#define BB 2
#define HH 1024
#define WW 1024
#define MU 5

__device__ __forceinline__ float fast_rcp(float x) { return __builtin_amdgcn_rcpf(x); }
__device__ __forceinline__ float fast_rsq(float x) { return __builtin_amdgcn_rsqf(x); }
// 1/(1+exp(-x))  ==  (tanh(x/2)+1)/2
__device__ __forceinline__ float sigm(float x) { return fast_rcp(1.f + __expf(-x)); }

// ---------------------------------------------------------------------------
// Kernel 1: Sobel + init tangent + raw mag + per-block max (NO global atomic).
// One block per (row, batch); 256 threads, 4 px/thread striped.
// ---------------------------------------------------------------------------
__global__ __launch_bounds__(256) void sobel_init(
    const float* __restrict__ x,
    float* __restrict__ tang,        // (B,2,H,W)
    float* __restrict__ mag,         // (B,H,W) raw
    float* __restrict__ block_max)   // (B*H)
{
    __shared__ float rows[3][WW + 8];   // data at [4..WW+4), zero halo both ends
    const int t = threadIdx.x;
    const int h = blockIdx.y, b = blockIdx.z;
    const size_t plane = (size_t)HH * WW;
    const float* xb = x + (size_t)b * plane;

    #pragma unroll
    for (int r = 0; r < 3; ++r) {
        int hh = h - 1 + r;
        float4 v = make_float4(0.f, 0.f, 0.f, 0.f);
        if (hh >= 0 && hh < HH) v = *(const float4*)(xb + (size_t)hh * WW + 4 * t);
        *(float4*)&rows[r][4 + 4 * t] = v;   // byte addr 16+16t: 16B aligned
        if (t < 4) { rows[r][t] = 0.f; rows[r][WW + 4 + t] = 0.f; }
    }
    __syncthreads();

    float* mp = mag + (size_t)b * plane + (size_t)h * WW;
    float* t0 = tang + ((size_t)b * 2 + 0) * plane + (size_t)h * WW;
    float* t1 = tang + ((size_t)b * 2 + 1) * plane + (size_t)h * WW;

    float lmax = 0.f;
    #pragma unroll
    for (int k = 0; k < 4; ++k) {
        int px = t + 256 * k;          // striped: consecutive lanes -> consecutive LDS addrs
        int c = 4 + px;
        float tl = rows[0][c - 1], tc = rows[0][c], tr = rows[0][c + 1];
        float ml = rows[1][c - 1],                  mr = rows[1][c + 1];
        float bl = rows[2][c - 1], bc = rows[2][c], br = rows[2][c + 1];
        float s0 = (bl - tl) + 2.f * (bc - tc) + (br - tr);   // k
        float s1 = (tr - tl) + 2.f * (mr - ml) + (br - bl);   // k^T
        float m = sqrtf(fmaf(s0, s0, s1 * s1));
        float inv = (m == 0.f) ? 1.f : fast_rcp(m);
        mp[px] = m;
        t0[px] = -s1 * inv;
        t1[px] =  s0 * inv;
        lmax = fmaxf(lmax, m);
    }

    #pragma unroll
    for (int off = 32; off; off >>= 1) lmax = fmaxf(lmax, __shfl_down(lmax, off, 64));
    __shared__ float smax[4];
    if ((t & 63) == 0) smax[t >> 6] = lmax;
    __syncthreads();
    if (t == 0) block_max[b * HH + h] = fmaxf(fmaxf(smax[0], smax[1]), fmaxf(smax[2], smax[3]));
}

// ---------------------------------------------------------------------------
// Kernel 2: reduce 2048 per-block maxes -> gmax. One block, no atomics.
// ---------------------------------------------------------------------------
__global__ __launch_bounds__(256) void reduce_max(
    const float* __restrict__ block_max, float* __restrict__ gmax)
{
    const int t = threadIdx.x;
    float m = 0.f;
    #pragma unroll
    for (int i = 0; i < 8; ++i) m = fmaxf(m, block_max[t + 256 * i]);
    #pragma unroll
    for (int off = 32; off; off >>= 1) m = fmaxf(m, __shfl_down(m, off, 64));
    __shared__ float smax[4];
    if ((t & 63) == 0) smax[t >> 6] = m;
    __syncthreads();
    if (t == 0) gmax[0] = fmaxf(fmaxf(smax[0], smax[1]), fmaxf(smax[2], smax[3]));
}

// ---------------------------------------------------------------------------
// Kernel 3a: vertical ETF pass. 4 consecutive px/thread, float4 global loads.
// Out-of-range rows contribute exactly 0 (reference zero-pads) -> skip.
// ---------------------------------------------------------------------------
__global__ __launch_bounds__(256) void etf_v(
    const float* __restrict__ tin, float* __restrict__ tout,
    const float* __restrict__ mag, const float* __restrict__ gmax)
{
    const int t = threadIdx.x;
    const int h = blockIdx.y, b = blockIdx.z;
    const size_t plane = (size_t)HH * WW;
    const float s2 = 2.f * fast_rcp(gmax[0]);   // sigmoid(s2*(myraw-mxraw)) == (tanh(my-mx)+1)/2
    const float* t0p = tin + ((size_t)b * 2 + 0) * plane;
    const float* t1p = tin + ((size_t)b * 2 + 1) * plane;
    const float* mp  = mag + (size_t)b * plane;
    const int col = 4 * t;

    float4 vx0 = *(const float4*)(t0p + (size_t)h * WW + col);
    float4 vx1 = *(const float4*)(t1p + (size_t)h * WW + col);
    float4 vmx = *(const float4*)(mp  + (size_t)h * WW + col);
    const float* tx0 = (const float*)&vx0;
    const float* tx1 = (const float*)&vx1;
    const float* mx  = (const float*)&vmx;

    float a0[4] = {0.f, 0.f, 0.f, 0.f};
    float a1[4] = {0.f, 0.f, 0.f, 0.f};

    #pragma unroll
    for (int d = -MU; d <= MU; ++d) {
        int hh = h + d;
        if (hh < 0 || hh >= HH) continue;
        float4 vy0 = *(const float4*)(t0p + (size_t)hh * WW + col);
        float4 vy1 = *(const float4*)(t1p + (size_t)hh * WW + col);
        float4 vmy = *(const float4*)(mp  + (size_t)hh * WW + col);
        const float* y0 = (const float*)&vy0;
        const float* y1 = (const float*)&vy1;
        const float* my = (const float*)&vmy;
        #pragma unroll
        for (int j = 0; j < 4; ++j) {
            float dt = fmaf(tx0[j], y0[j], tx1[j] * y1[j]);
            float w  = sigm(s2 * (my[j] - mx[j])) * dt;
            a0[j] = fmaf(y0[j], w, a0[j]);
            a1[j] = fmaf(y1[j], w, a1[j]);
        }
    }

    float4 o0, o1;
    float* p0 = (float*)&o0; float* p1 = (float*)&o1;
    #pragma unroll
    for (int j = 0; j < 4; ++j) {
        float n2 = fmaf(a0[j], a0[j], a1[j] * a1[j]);
        float inv = (n2 == 0.f) ? 1.f : fast_rsq(n2);
        p0[j] = a0[j] * inv;
        p1[j] = a1[j] * inv;
    }
    *(float4*)(tout + ((size_t)b * 2 + 0) * plane + (size_t)h * WW + col) = o0;
    *(float4*)(tout + ((size_t)b * 2 + 1) * plane + (size_t)h * WW + col) = o1;
}

// ---------------------------------------------------------------------------
// Kernel 3b: horizontal ETF pass. Row staged in LDS (halo=8, zero-padded);
// 4 px/thread striped -> conflict-free LDS reads, coalesced scalar stores.
// ---------------------------------------------------------------------------
__global__ __launch_bounds__(256) void etf_h(
    const float* __restrict__ tin, float* __restrict__ tout,
    const float* __restrict__ mag, const float* __restrict__ gmax)
{
    __shared__ float lt0[WW + 16], lt1[WW + 16], lm[WW + 16];  // data at [8..WW+8)
    const int t = threadIdx.x;
    const int h = blockIdx.y, b = blockIdx.z;
    const size_t plane = (size_t)HH * WW;
    const float* t0p = tin + ((size_t)b * 2 + 0) * plane + (size_t)h * WW;
    const float* t1p = tin + ((size_t)b * 2 + 1) * plane + (size_t)h * WW;
    const float* mp  = mag + (size_t)b * plane + (size_t)h * WW;

    *(float4*)&lt0[8 + 4 * t] = *(const float4*)(t0p + 4 * t);  // byte 32+16t: aligned
    *(float4*)&lt1[8 + 4 * t] = *(const float4*)(t1p + 4 * t);
    *(float4*)&lm [8 + 4 * t] = *(const float4*)(mp  + 4 * t);
    if (t < 8) {
        lt0[t] = 0.f; lt1[t] = 0.f; lm[t] = 0.f;
        lt0[WW + 8 + t] = 0.f; lt1[WW + 8 + t] = 0.f; lm[WW + 8 + t] = 0.f;
    }
    __syncthreads();

    const float s2 = 2.f * fast_rcp(gmax[0]);
    float* o0 = tout + ((size_t)b * 2 + 0) * plane + (size_t)h * WW;
    float* o1 = tout + ((size_t)b * 2 + 1) * plane + (size_t)h * WW;

    #pragma unroll
    for (int k = 0; k < 4; ++k) {
        int px = t + 256 * k;
        int c = 8 + px;
        float tx0 = lt0[c], tx1 = lt1[c], mx = lm[c];
        float a0 = 0.f, a1 = 0.f;
        #pragma unroll
        for (int d = -MU; d <= MU; ++d) {
            int i = c + d;                       // zero halo: OOB taps contribute 0
            float y0 = lt0[i], y1 = lt1[i], my = lm[i];
            float dt = fmaf(tx0, y0, tx1 * y1);
            float w  = sigm(s2 * (my - mx)) * dt;
            a0 = fmaf(y0, w, a0);
            a1 = fmaf(y1, w, a1);
        }
        float n2 = fmaf(a0, a0, a1 * a1);
        float inv = (n2 == 0.f) ? 1.f : fast_rsq(n2);
        o0[px] = a0 * inv;
        o1[px] = a1 * inv;
    }
}

extern "C" void kernel_launch(void* const* d_in, const int* in_sizes, int n_in,
                              void* d_out, int out_size, void* d_ws, size_t ws_size,
                              hipStream_t stream)
{
    const float* x = (const float*)d_in[0];   // (2,1,1024,1024) fp32
    float* tangA = (float*)d_out;
    char* ws = (char*)d_ws;
    const size_t plane = (size_t)HH * WW;

    float* tangB = (float*)ws;                                     // 16 MB
    float* mag   = (float*)(ws + sizeof(float) * BB * 2 * plane);  // 8 MB
    float* gmax  = (float*)(ws + sizeof(float) * BB * 3 * plane);  // 4 B
    // block_max aliases tangB[0..2048): fully consumed by reduce_max before
    // the first pass writes tangB.
    float* block_max = tangB;

    dim3 blk(256, 1, 1);
    dim3 grd(1, HH, BB);

    sobel_init<<<grd, blk, 0, stream>>>(x, tangA, mag, block_max);
    reduce_max<<<dim3(1), blk, 0, stream>>>(block_max, gmax);

    etf_v<<<grd, blk, 0, stream>>>(tangA, tangB, mag, gmax);
    etf_h<<<grd, blk, 0, stream>>>(tangB, tangA, mag, gmax);
    etf_v<<<grd, blk, 0, stream>>>(tangA, tangB, mag, gmax);
    etf_h<<<grd, blk, 0, stream>>>(tangB, tangA, mag, gmax);
    etf_v<<<grd, blk, 0, stream>>>(tangA, tangB, mag, gmax);
    etf_h<<<grd, blk, 0, stream>>>(tangB, tangA, mag, gmax);
}

// Round 3
// 156.912 us; speedup vs baseline: 1.8966x; 1.6108x over previous
//
#include <hip/hip_runtime.h>

#define BB 2
#define HH 1024
#define WW 1024
#define MU 5

__device__ __forceinline__ float fast_rcp(float x) { return __builtin_amdgcn_rcpf(x); }
__device__ __forceinline__ float fast_rsq(float x) { return __builtin_amdgcn_rsqf(x); }
// (tanh(d)+1)/2 == 1/(1+exp(-2d)); scale folded by caller
__device__ __forceinline__ float sigm(float x) { return fast_rcp(1.f + __expf(-x)); }

// ---------------------------------------------------------------------------
// Kernel 1: Sobel + init tangent + raw mag + per-block max.
// 8 output rows per block, 10-row full-width LDS stage (over-fetch 1.25x).
// ---------------------------------------------------------------------------
#define SROWS 8
__global__ __launch_bounds__(256) void sobel_init(
    const float* __restrict__ x,
    float* __restrict__ tang,        // (B,2,H,W)
    float* __restrict__ mag,         // (B,H,W) raw
    float* __restrict__ block_max)   // (128*B)
{
    __shared__ float rows[SROWS + 2][WW + 8];   // data at [4..WW+4), zero halo
    const int t = threadIdx.x;
    const int h0 = blockIdx.x * SROWS;
    const int b = blockIdx.y;
    const size_t plane = (size_t)HH * WW;
    const float* xb = x + (size_t)b * plane;

    #pragma unroll
    for (int i = 0; i < SROWS + 2; ++i) {
        int g = h0 - 1 + i;
        float4 v = make_float4(0.f, 0.f, 0.f, 0.f);
        if (g >= 0 && g < HH) v = *(const float4*)(xb + (size_t)g * WW + 4 * t);
        *(float4*)&rows[i][4 + 4 * t] = v;      // byte 16+16t: aligned
    }
    if (t < 4) {
        #pragma unroll
        for (int i = 0; i < SROWS + 2; ++i) { rows[i][t] = 0.f; rows[i][WW + 4 + t] = 0.f; }
    }
    __syncthreads();

    float lmax = 0.f;
    #pragma unroll
    for (int k = 0; k < SROWS; ++k) {
        const float* rT = rows[k], * rM = rows[k + 1], * rB = rows[k + 2];
        float* mp = mag + (size_t)b * plane + (size_t)(h0 + k) * WW;
        float* t0 = tang + ((size_t)b * 2 + 0) * plane + (size_t)(h0 + k) * WW;
        float* t1 = tang + ((size_t)b * 2 + 1) * plane + (size_t)(h0 + k) * WW;
        #pragma unroll
        for (int j = 0; j < 4; ++j) {
            int px = t + 256 * j;               // striped: conflict-free LDS
            int c = 4 + px;
            float tl = rT[c - 1], tc = rT[c], tr = rT[c + 1];
            float ml = rM[c - 1],               mr = rM[c + 1];
            float bl = rB[c - 1], bc = rB[c], br = rB[c + 1];
            float s0 = (bl - tl) + 2.f * (bc - tc) + (br - tr);   // k
            float s1 = (tr - tl) + 2.f * (mr - ml) + (br - bl);   // k^T
            float m = sqrtf(fmaf(s0, s0, s1 * s1));
            float inv = (m == 0.f) ? 1.f : fast_rcp(m);
            mp[px] = m;
            t0[px] = -s1 * inv;
            t1[px] =  s0 * inv;
            lmax = fmaxf(lmax, m);
        }
    }

    #pragma unroll
    for (int off = 32; off; off >>= 1) lmax = fmaxf(lmax, __shfl_down(lmax, off, 64));
    __shared__ float smax[4];
    if ((t & 63) == 0) smax[t >> 6] = lmax;
    __syncthreads();
    if (t == 0)
        block_max[blockIdx.y * (HH / SROWS) + blockIdx.x] =
            fmaxf(fmaxf(smax[0], smax[1]), fmaxf(smax[2], smax[3]));
}

// ---------------------------------------------------------------------------
// Kernel 2: reduce 256 per-block maxes -> gmax.
// ---------------------------------------------------------------------------
__global__ __launch_bounds__(256) void reduce_max(
    const float* __restrict__ block_max, float* __restrict__ gmax)
{
    const int t = threadIdx.x;
    float m = block_max[t];
    #pragma unroll
    for (int off = 32; off; off >>= 1) m = fmaxf(m, __shfl_down(m, off, 64));
    __shared__ float smax[4];
    if ((t & 63) == 0) smax[t >> 6] = m;
    __syncthreads();
    if (t == 0) gmax[0] = fmaxf(fmaxf(smax[0], smax[1]), fmaxf(smax[2], smax[3]));
}

// ---------------------------------------------------------------------------
// Kernel 3a: vertical ETF pass, 2D tiled. Tile 64 cols x 32 rows out,
// LDS stage (32+10) rows x 64 cols x {t0,t1,mag}. Zero rows in vertical halo
// reproduce reference zero-padding exactly (dot=0 -> contribution 0).
// ---------------------------------------------------------------------------
#define TW 64
#define TH 32
__global__ __launch_bounds__(256) void etf_v(
    const float* __restrict__ tin, float* __restrict__ tout,
    const float* __restrict__ mag, const float* __restrict__ gmax)
{
    __shared__ float ls[3][TH + 10][TW + 4];    // row stride 68 floats (272B, 16B-aligned)
    const int t = threadIdx.x;
    const int w0 = blockIdx.x * TW;
    const int h0 = blockIdx.y * TH;
    const int b = blockIdx.z;
    const size_t plane = (size_t)HH * WW;
    const float* t0p = tin + ((size_t)b * 2 + 0) * plane;
    const float* t1p = tin + ((size_t)b * 2 + 1) * plane;
    const float* mp  = mag + (size_t)b * plane;

    const int c4 = (t & 15) * 4;                // col within tile (float4)
    const int rg = t >> 4;                      // 16 rows per sweep
    #pragma unroll
    for (int rr = rg; rr < TH + 10; rr += 16) {
        int g = h0 - MU + rr;
        float4 v0 = make_float4(0.f, 0.f, 0.f, 0.f), v1 = v0, vm = v0;
        if (g >= 0 && g < HH) {
            size_t base = (size_t)g * WW + w0 + c4;
            v0 = *(const float4*)(t0p + base);
            v1 = *(const float4*)(t1p + base);
            vm = *(const float4*)(mp + base);
        }
        *(float4*)&ls[0][rr][c4] = v0;
        *(float4*)&ls[1][rr][c4] = v1;
        *(float4*)&ls[2][rr][c4] = vm;
    }
    __syncthreads();

    const float s2 = 2.f * fast_rcp(gmax[0]);

    #pragma unroll
    for (int k = 0; k < TH / 16; ++k) {
        const int ro = (t >> 4) + 16 * k;       // output row within tile
        float4 vx0 = *(const float4*)&ls[0][ro + MU][c4];
        float4 vx1 = *(const float4*)&ls[1][ro + MU][c4];
        float4 vxm = *(const float4*)&ls[2][ro + MU][c4];
        const float* tx0 = (const float*)&vx0;
        const float* tx1 = (const float*)&vx1;
        const float* txm = (const float*)&vxm;

        float a0[4] = {0.f, 0.f, 0.f, 0.f};
        float a1[4] = {0.f, 0.f, 0.f, 0.f};
        #pragma unroll
        for (int d = 0; d <= 2 * MU; ++d) {
            float4 vy0 = *(const float4*)&ls[0][ro + d][c4];
            float4 vy1 = *(const float4*)&ls[1][ro + d][c4];
            float4 vym = *(const float4*)&ls[2][ro + d][c4];
            const float* y0 = (const float*)&vy0;
            const float* y1 = (const float*)&vy1;
            const float* ym = (const float*)&vym;
            #pragma unroll
            for (int j = 0; j < 4; ++j) {
                float dt = fmaf(tx0[j], y0[j], tx1[j] * y1[j]);
                float w  = sigm(s2 * (ym[j] - txm[j])) * dt;
                a0[j] = fmaf(y0[j], w, a0[j]);
                a1[j] = fmaf(y1[j], w, a1[j]);
            }
        }

        float4 o0, o1;
        float* p0 = (float*)&o0; float* p1 = (float*)&o1;
        #pragma unroll
        for (int j = 0; j < 4; ++j) {
            float n2 = fmaf(a0[j], a0[j], a1[j] * a1[j]);
            float inv = (n2 == 0.f) ? 1.f : fast_rsq(n2);
            p0[j] = a0[j] * inv;
            p1[j] = a1[j] * inv;
        }
        size_t obase = (size_t)(h0 + ro) * WW + w0 + c4;
        *(float4*)(tout + ((size_t)b * 2 + 0) * plane + obase) = o0;
        *(float4*)(tout + ((size_t)b * 2 + 1) * plane + obase) = o1;
    }
}

// ---------------------------------------------------------------------------
// Kernel 3b: horizontal ETF pass. Row staged in LDS (halo=8, zero-padded).
// ---------------------------------------------------------------------------
__global__ __launch_bounds__(256) void etf_h(
    const float* __restrict__ tin, float* __restrict__ tout,
    const float* __restrict__ mag, const float* __restrict__ gmax)
{
    __shared__ float lt0[WW + 16], lt1[WW + 16], lm[WW + 16];  // data at [8..WW+8)
    const int t = threadIdx.x;
    const int h = blockIdx.x, b = blockIdx.y;
    const size_t plane = (size_t)HH * WW;
    const float* t0p = tin + ((size_t)b * 2 + 0) * plane + (size_t)h * WW;
    const float* t1p = tin + ((size_t)b * 2 + 1) * plane + (size_t)h * WW;
    const float* mp  = mag + (size_t)b * plane + (size_t)h * WW;

    *(float4*)&lt0[8 + 4 * t] = *(const float4*)(t0p + 4 * t);
    *(float4*)&lt1[8 + 4 * t] = *(const float4*)(t1p + 4 * t);
    *(float4*)&lm [8 + 4 * t] = *(const float4*)(mp  + 4 * t);
    if (t < 8) {
        lt0[t] = 0.f; lt1[t] = 0.f; lm[t] = 0.f;
        lt0[WW + 8 + t] = 0.f; lt1[WW + 8 + t] = 0.f; lm[WW + 8 + t] = 0.f;
    }
    __syncthreads();

    const float s2 = 2.f * fast_rcp(gmax[0]);
    float* o0 = tout + ((size_t)b * 2 + 0) * plane + (size_t)h * WW;
    float* o1 = tout + ((size_t)b * 2 + 1) * plane + (size_t)h * WW;

    #pragma unroll
    for (int k = 0; k < 4; ++k) {
        int px = t + 256 * k;
        int c = 8 + px;
        float tx0 = lt0[c], tx1 = lt1[c], mx = lm[c];
        float a0 = 0.f, a1 = 0.f;
        #pragma unroll
        for (int d = -MU; d <= MU; ++d) {
            int i = c + d;
            float y0 = lt0[i], y1 = lt1[i], my = lm[i];
            float dt = fmaf(tx0, y0, tx1 * y1);
            float w  = sigm(s2 * (my - mx)) * dt;
            a0 = fmaf(y0, w, a0);
            a1 = fmaf(y1, w, a1);
        }
        float n2 = fmaf(a0, a0, a1 * a1);
        float inv = (n2 == 0.f) ? 1.f : fast_rsq(n2);
        o0[px] = a0 * inv;
        o1[px] = a1 * inv;
    }
}

extern "C" void kernel_launch(void* const* d_in, const int* in_sizes, int n_in,
                              void* d_out, int out_size, void* d_ws, size_t ws_size,
                              hipStream_t stream)
{
    const float* x = (const float*)d_in[0];   // (2,1,1024,1024) fp32
    float* tangA = (float*)d_out;
    char* ws = (char*)d_ws;
    const size_t plane = (size_t)HH * WW;

    float* tangB = (float*)ws;                                         // 16 MB
    float* mag   = (float*)(ws + sizeof(float) * BB * 2 * plane);      // 8 MB
    float* gmax  = (float*)(ws + sizeof(float) * BB * 3 * plane);      // 4 B
    float* block_max = gmax + 16;                                      // 256 floats

    dim3 blk(256, 1, 1);

    sobel_init<<<dim3(HH / SROWS, BB), blk, 0, stream>>>(x, tangA, mag, block_max);
    reduce_max<<<dim3(1), blk, 0, stream>>>(block_max, gmax);

    dim3 gv(WW / TW, HH / TH, BB);
    dim3 gh(HH, BB);
    etf_v<<<gv, blk, 0, stream>>>(tangA, tangB, mag, gmax);
    etf_h<<<gh, blk, 0, stream>>>(tangB, tangA, mag, gmax);
    etf_v<<<gv, blk, 0, stream>>>(tangA, tangB, mag, gmax);
    etf_h<<<gh, blk, 0, stream>>>(tangB, tangA, mag, gmax);
    etf_v<<<gv, blk, 0, stream>>>(tangA, tangB, mag, gmax);
    etf_h<<<gh, blk, 0, stream>>>(tangB, tangA, mag, gmax);
}